// Round 4
// baseline (1552.569 us; speedup 1.0000x reference)
//
#include <hip/hip_runtime.h>
#include <math.h>

#define WIDTH 768
#define HEADS 12
#define HD 64
#define MINI 16
#define NSEQ 4096
#define BATCH 4
#define NMB (NSEQ/MINI)
#define EPS 1e-6f

typedef __attribute__((ext_vector_type(8))) short bf16x8;
typedef __attribute__((ext_vector_type(4))) float f32x4;
typedef __attribute__((ext_vector_type(4))) int   i32x4;

__device__ __forceinline__ float bfu2f(unsigned short h) {
    return __uint_as_float(((unsigned)h) << 16);
}
// truncation-based split: f = hi + lo to ~2^-16 relative
__device__ __forceinline__ void tsplit(float f, unsigned short& h, unsigned short& l) {
    unsigned uh = __float_as_uint(f) & 0xffff0000u;
    h = (unsigned short)(uh >> 16);
    l = (unsigned short)(__float_as_uint(f - __uint_as_float(uh)) >> 16);
}
__device__ __forceinline__ unsigned tpack(float f) {
    unsigned uh = __float_as_uint(f) & 0xffff0000u;
    return uh | (__float_as_uint(f - __uint_as_float(uh)) >> 16);
}
// wave-private LDS fence: drain LDS ops, keep global prefetch (vmcnt) in flight.
// rule 18: sched_barrier(0) after inline-asm lgkmcnt so MFMAs can't hoist past.
__device__ __forceinline__ void fence_lds() {
    asm volatile("s_waitcnt lgkmcnt(0)" ::: "memory");
    __builtin_amdgcn_sched_barrier(0);
}

// ---------------- shared-memory overlays ----------------
struct ScanSM1 {                // single-wave scan, wave-private (27648 B)
    unsigned sXKp[16 * 68];     // packed hi|lo XK, [m][k]
    unsigned sGE[16 * 68];      // packed grad_e, [m][j]
    unsigned sCB[16 * 20];      // packed -C', [m][i]
    float    sUw[64 * 68];      // W1 update, [j][k] (transposed: b128 both sides)
    float    sB1d[64];
};
struct GemmSM {
    unsigned short sAh[128 * 40], sAl[128 * 40];
    unsigned short sBh[128 * 40], sBl[128 * 40];
};
struct WtSM { float sT[64][65]; };
#define SMEM_BYTES 40960   // sizeof(GemmSM) is the max

// ---------------- transpose + split weight tile: w[K][N] -> hiT/loT[N][K] ----------------
__device__ void wtconv_body(char* smraw, int tid, int n0, int k0, const float* __restrict__ w,
                            unsigned short* __restrict__ hiT, unsigned short* __restrict__ loT)
{
    WtSM* W = (WtSM*)smraw;
    int t = tid, r = t >> 2, cs = (t & 3) * 16;
#pragma unroll
    for (int i = 0; i < 16; i += 4)
        *(float4*)&W->sT[r][cs + i] = *(const float4*)&w[(size_t)(k0 + r) * WIDTH + n0 + cs + i];
    __syncthreads();
    ushort4 hb[4], lb[4];
#pragma unroll
    for (int i = 0; i < 16; i++) {
        unsigned short hh, ll;
        tsplit(W->sT[cs + i][r], hh, ll);
        ((unsigned short*)hb)[i] = hh;
        ((unsigned short*)lb)[i] = ll;
    }
#pragma unroll
    for (int i = 0; i < 4; i++) {
        *(ushort4*)&hiT[(size_t)(n0 + r) * WIDTH + k0 + cs + i * 4] = hb[i];
        *(ushort4*)&loT[(size_t)(n0 + r) * WIDTH + k0 + cs + i * 4] = lb[i];
    }
}

// ---------------- split-bf16 3-term MFMA GEMM body (256 thr, 128x128) ----------------
template<int ACT, int SPLITA>
__device__ void gemm_body(char* smraw, int tid, int by,
                          const float* __restrict__ Af,
                          const unsigned short* __restrict__ APh,
                          const unsigned short* __restrict__ APl,
                          const unsigned short* __restrict__ BhT,
                          const unsigned short* __restrict__ BlT,
                          float* __restrict__ C, int ldc, int K)
{
    GemmSM* g = (GemmSM*)smraw;
    const int bm = by * 128;
    const int w = tid >> 6, lane = tid & 63, quad = lane >> 4, m16 = lane & 15;
    const int mw = (w & 1) * 64, nw = (w >> 1) * 64;
    const int srow = tid >> 1, sseg = (tid & 1) * 16;
    f32x4 acc[4][4];
#pragma unroll
    for (int a = 0; a < 4; a++)
#pragma unroll
        for (int c = 0; c < 4; c++) acc[a][c] = (f32x4){0.f, 0.f, 0.f, 0.f};

    for (int k0 = 0; k0 < K; k0 += 32) {
        uint4 vb0 = *(const uint4*)(BhT + (size_t)srow * K + k0 + sseg);
        uint4 vb1 = *(const uint4*)(BhT + (size_t)srow * K + k0 + sseg + 8);
        uint4 vd0 = *(const uint4*)(BlT + (size_t)srow * K + k0 + sseg);
        uint4 vd1 = *(const uint4*)(BlT + (size_t)srow * K + k0 + sseg + 8);
        if (SPLITA) {
            const float* Ap = Af + (size_t)(bm + srow) * K + k0 + sseg;
            float4 f0 = *(const float4*)(Ap);
            float4 f1 = *(const float4*)(Ap + 4);
            float4 f2 = *(const float4*)(Ap + 8);
            float4 f3 = *(const float4*)(Ap + 12);
            __syncthreads();
            unsigned short hs[16], ls[16];
            float fv[16] = {f0.x, f0.y, f0.z, f0.w, f1.x, f1.y, f1.z, f1.w,
                            f2.x, f2.y, f2.z, f2.w, f3.x, f3.y, f3.z, f3.w};
#pragma unroll
            for (int i = 0; i < 16; i++) tsplit(fv[i], hs[i], ls[i]);
            *(uint4*)&g->sAh[srow * 40 + sseg]     = *(uint4*)&hs[0];
            *(uint4*)&g->sAh[srow * 40 + sseg + 8] = *(uint4*)&hs[8];
            *(uint4*)&g->sAl[srow * 40 + sseg]     = *(uint4*)&ls[0];
            *(uint4*)&g->sAl[srow * 40 + sseg + 8] = *(uint4*)&ls[8];
        } else {
            uint4 va0 = *(const uint4*)(APh + (size_t)(bm + srow) * K + k0 + sseg);
            uint4 va1 = *(const uint4*)(APh + (size_t)(bm + srow) * K + k0 + sseg + 8);
            uint4 vc0 = *(const uint4*)(APl + (size_t)(bm + srow) * K + k0 + sseg);
            uint4 vc1 = *(const uint4*)(APl + (size_t)(bm + srow) * K + k0 + sseg + 8);
            __syncthreads();
            *(uint4*)&g->sAh[srow * 40 + sseg] = va0; *(uint4*)&g->sAh[srow * 40 + sseg + 8] = va1;
            *(uint4*)&g->sAl[srow * 40 + sseg] = vc0; *(uint4*)&g->sAl[srow * 40 + sseg + 8] = vc1;
        }
        *(uint4*)&g->sBh[srow * 40 + sseg] = vb0; *(uint4*)&g->sBh[srow * 40 + sseg + 8] = vb1;
        *(uint4*)&g->sBl[srow * 40 + sseg] = vd0; *(uint4*)&g->sBl[srow * 40 + sseg + 8] = vd1;
        __syncthreads();
        bf16x8 ah[4], al[4];
#pragma unroll
        for (int mt = 0; mt < 4; mt++) {
            ah[mt] = *(const bf16x8*)&g->sAh[(mw + mt * 16 + m16) * 40 + quad * 8];
            al[mt] = *(const bf16x8*)&g->sAl[(mw + mt * 16 + m16) * 40 + quad * 8];
        }
#pragma unroll
        for (int nt = 0; nt < 4; nt++) {
            bf16x8 bh8 = *(const bf16x8*)&g->sBh[(nw + nt * 16 + m16) * 40 + quad * 8];
            bf16x8 bl8 = *(const bf16x8*)&g->sBl[(nw + nt * 16 + m16) * 40 + quad * 8];
#pragma unroll
            for (int mt = 0; mt < 4; mt++) {
                acc[mt][nt] = __builtin_amdgcn_mfma_f32_16x16x32_bf16(ah[mt], bh8, acc[mt][nt], 0, 0, 0);
                acc[mt][nt] = __builtin_amdgcn_mfma_f32_16x16x32_bf16(al[mt], bh8, acc[mt][nt], 0, 0, 0);
                acc[mt][nt] = __builtin_amdgcn_mfma_f32_16x16x32_bf16(ah[mt], bl8, acc[mt][nt], 0, 0, 0);
            }
        }
    }
#pragma unroll
    for (int mt = 0; mt < 4; mt++)
#pragma unroll
        for (int nt = 0; nt < 4; nt++)
#pragma unroll
            for (int r = 0; r < 4; r++) {
                float v = acc[mt][nt][r];
                if (ACT == 1) {
                    float inner = 0.7978845608028654f * (v + 0.044715f * v * v * v);
                    v = 0.5f * v * (1.0f + tanhf(inner));
                }
                C[(size_t)(bm + mw + mt * 16 + quad * 4 + r) * ldc + nw + nt * 16 + m16] = v;
            }
}

// ============ TTT scan v7: ONE WAVE per head — zero barriers ============
// lane = (quad, m16): token col = m16; j rows covered by 4 jt-tiles x quad*4+r.
// All LayerNorm reductions are intra-wave shfl_xor(16/32). LDS is wave-private,
// ordered by lgkmcnt fences only. Layout mappings identical to the verified
// 4-wave version with wave-index w replaced by compile-time tile index.
__device__ void scan_wave(char* smraw, int lane, int bh,
    const unsigned short* __restrict__ XQh, const unsigned short* __restrict__ XQl,
    const unsigned short* __restrict__ XKh, const unsigned short* __restrict__ XKl,
    const float* __restrict__ XVb, const float* __restrict__ lr_buf,
    const float* __restrict__ W1g, const float* __restrict__ b1g,
    const float* __restrict__ gln, const float* __restrict__ blnv,
    const float* __restrict__ lti, float* __restrict__ out)
{
    ScanSM1* S = (ScanSM1*)smraw;
    const int quad = lane >> 4, m16 = lane & 15;
    const int b = bh / HEADS, h = bh - b * HEADS;

    // per-lane LN constants for all 4 j-tiles
    float g4[4][4], b4[4][4], gg4[4][4], b1v[4][4];
#pragma unroll
    for (int jt = 0; jt < 4; jt++)
#pragma unroll
        for (int r = 0; r < 4; r++) {
            int j = 16 * jt + quad * 4 + r;
            g4[jt][r] = gln[h * 64 + j];
            b4[jt][r] = blnv[h * 64 + j];
            b1v[jt][r] = b1g[h * 64 + j];
            gg4[jt][r] = g4[jt][r] * g4[jt][r];
        }
    const float tok15 = fmaxf(1.0f / 16.0f + lti[15], 0.0f);
    float tki[4];
#pragma unroll
    for (int r = 0; r < 4; r++)
        tki[r] = fmaxf(1.0f / (float)(quad * 4 + r + 1) + lti[quad * 4 + r], 0.0f) / tok15;

    // Ag2 = sum_j g_j^2 — intra-wave
    float ags = 0.f;
#pragma unroll
    for (int jt = 0; jt < 4; jt++)
        ags += (gg4[jt][0] + gg4[jt][1]) + (gg4[jt][2] + gg4[jt][3]);
    ags += __shfl_xor(ags, 16); ags += __shfl_xor(ags, 32);
    const float Ag2 = ags;

    // W1 master fp32 at B-frag positions [k=kt*32+quad*8+e][j=16jt+m16]
    float W1f[4][2][8]; bf16x8 w1h[4][2], w1l[4][2];
#pragma unroll
    for (int jt = 0; jt < 4; jt++)
#pragma unroll
        for (int kt = 0; kt < 2; kt++)
#pragma unroll
            for (int e = 0; e < 8; e++) {
                float f = W1g[h * 4096 + (kt * 32 + quad * 8 + e) * 64 + 16 * jt + m16];
                W1f[jt][kt][e] = f;
                unsigned short hh, ll; tsplit(f, hh, ll);
                w1h[jt][kt][e] = (short)hh; w1l[jt][kt][e] = (short)ll;
            }

    const unsigned short* xqh = XQh + (size_t)bh * NSEQ * 64;
    const unsigned short* xql = XQl + (size_t)bh * NSEQ * 64;
    const unsigned short* xkh = XKh + (size_t)bh * NSEQ * 64;
    const unsigned short* xkl = XKl + (size_t)bh * NSEQ * 64;
    const float* xvB = XVb + (size_t)b * NSEQ * WIDTH + h * 64;
    const float* lrB = lr_buf + (size_t)bh * NSEQ;
    float* outB = out + (size_t)b * NSEQ * WIDTH + h * 64;

    bf16x8 ones8;
#pragma unroll
    for (int e = 0; e < 8; e++) ones8[e] = (short)0x3F80;

    // prefetch step 0
    bf16x8 pqh[2], pql[2], pkh[2], pkl[2];
    float4 pxv[4]; ushort4 pth[4], ptl[4]; float plr;
    {
        const size_t tok = m16;
#pragma unroll
        for (int kt = 0; kt < 2; kt++) {
            pqh[kt] = *(const bf16x8*)(xqh + tok * 64 + kt * 32 + quad * 8);
            pql[kt] = *(const bf16x8*)(xql + tok * 64 + kt * 32 + quad * 8);
            pkh[kt] = *(const bf16x8*)(xkh + tok * 64 + kt * 32 + quad * 8);
            pkl[kt] = *(const bf16x8*)(xkl + tok * 64 + kt * 32 + quad * 8);
        }
#pragma unroll
        for (int jt = 0; jt < 4; jt++) {
            pxv[jt] = *(const float4*)(xvB + tok * WIDTH + 16 * jt + quad * 4);
            pth[jt] = *(const ushort4*)(xkh + tok * 64 + 16 * jt + quad * 4);
            ptl[jt] = *(const ushort4*)(xkl + tok * 64 + 16 * jt + quad * 4);
        }
        plr = lrB[m16];
    }

    for (int s = 0; s < NMB; s++) {
        bf16x8 qh[2] = {pqh[0], pqh[1]}, ql[2] = {pql[0], pql[1]};
        bf16x8 kh[2] = {pkh[0], pkh[1]}, kl[2] = {pkl[0], pkl[1]};
        float xv[4][4], xkt[4][4];
#pragma unroll
        for (int jt = 0; jt < 4; jt++) {
            xv[jt][0] = pxv[jt].x; xv[jt][1] = pxv[jt].y;
            xv[jt][2] = pxv[jt].z; xv[jt][3] = pxv[jt].w;
            xkt[jt][0] = bfu2f(pth[jt].x) + bfu2f(ptl[jt].x);
            xkt[jt][1] = bfu2f(pth[jt].y) + bfu2f(ptl[jt].y);
            xkt[jt][2] = bfu2f(pth[jt].z) + bfu2f(ptl[jt].z);
            xkt[jt][3] = bfu2f(pth[jt].w) + bfu2f(ptl[jt].w);
        }
        const float sc = tok15 * plr;

        // stage sXKp [m][k] (packed hi|lo of XK row m16) — read after fence 1
#pragma unroll
        for (int kt = 0; kt < 2; kt++) {
            i32x4 p0, p1;
#pragma unroll
            for (int e = 0; e < 4; e++)
                p0[e] = (int)((((unsigned)(unsigned short)kh[kt][e]) << 16) | (unsigned short)kl[kt][e]);
#pragma unroll
            for (int e = 0; e < 4; e++)
                p1[e] = (int)((((unsigned)(unsigned short)kh[kt][4 + e]) << 16) | (unsigned short)kl[kt][4 + e]);
            *(i32x4*)&S->sXKp[m16 * 68 + kt * 32 + quad * 8] = p0;
            *(i32x4*)&S->sXKp[m16 * 68 + kt * 32 + quad * 8 + 4] = p1;
        }

        // prefetch next step (vmcnt stays in flight; fences are lgkm-only)
        {
            const int sn = (s + 1 < NMB) ? s + 1 : s;
            const size_t tok = (size_t)sn * 16 + m16;
#pragma unroll
            for (int kt = 0; kt < 2; kt++) {
                pqh[kt] = *(const bf16x8*)(xqh + tok * 64 + kt * 32 + quad * 8);
                pql[kt] = *(const bf16x8*)(xql + tok * 64 + kt * 32 + quad * 8);
                pkh[kt] = *(const bf16x8*)(xkh + tok * 64 + kt * 32 + quad * 8);
                pkl[kt] = *(const bf16x8*)(xkl + tok * 64 + kt * 32 + quad * 8);
            }
#pragma unroll
            for (int jt = 0; jt < 4; jt++) {
                pxv[jt] = *(const float4*)(xvB + tok * WIDTH + 16 * jt + quad * 4);
                pth[jt] = *(const ushort4*)(xkh + tok * 64 + 16 * jt + quad * 4);
                ptl[jt] = *(const ushort4*)(xkl + tok * 64 + 16 * jt + quad * 4);
            }
            plr = lrB[(size_t)sn * 16 + m16];
        }
        // XQ residual for the output (consumed late; issue now, vmcnt hides it)
        ushort4 qoh[4], qol[4];
        {
            const size_t tokc = (size_t)s * 16 + m16;
#pragma unroll
            for (int jt = 0; jt < 4; jt++) {
                qoh[jt] = *(const ushort4*)(xqh + tokc * 64 + 16 * jt + quad * 4);
                qol[jt] = *(const ushort4*)(xql + tokc * 64 + 16 * jt + quad * 4);
            }
        }

        // phase 1: Z1^T (4 jt), ZQ^T (4 jt), Attn — 54 MFMAs, 9 independent chains
        f32x4 z1[4], zq[4];
#pragma unroll
        for (int jt = 0; jt < 4; jt++) { z1[jt] = (f32x4){0.f,0.f,0.f,0.f}; zq[jt] = (f32x4){0.f,0.f,0.f,0.f}; }
        f32x4 at = {0.f, 0.f, 0.f, 0.f};
        __builtin_amdgcn_s_setprio(1);
#pragma unroll
        for (int kt = 0; kt < 2; kt++) {
#pragma unroll
            for (int jt = 0; jt < 4; jt++) {
                z1[jt] = __builtin_amdgcn_mfma_f32_16x16x32_bf16(w1h[jt][kt], kh[kt], z1[jt], 0, 0, 0);
                z1[jt] = __builtin_amdgcn_mfma_f32_16x16x32_bf16(w1h[jt][kt], kl[kt], z1[jt], 0, 0, 0);
                z1[jt] = __builtin_amdgcn_mfma_f32_16x16x32_bf16(w1l[jt][kt], kh[kt], z1[jt], 0, 0, 0);
                zq[jt] = __builtin_amdgcn_mfma_f32_16x16x32_bf16(w1h[jt][kt], qh[kt], zq[jt], 0, 0, 0);
                zq[jt] = __builtin_amdgcn_mfma_f32_16x16x32_bf16(w1h[jt][kt], ql[kt], zq[jt], 0, 0, 0);
                zq[jt] = __builtin_amdgcn_mfma_f32_16x16x32_bf16(w1l[jt][kt], qh[kt], zq[jt], 0, 0, 0);
            }
            at = __builtin_amdgcn_mfma_f32_16x16x32_bf16(qh[kt], kh[kt], at, 0, 0, 0);
            at = __builtin_amdgcn_mfma_f32_16x16x32_bf16(qh[kt], kl[kt], at, 0, 0, 0);
            at = __builtin_amdgcn_mfma_f32_16x16x32_bf16(ql[kt], kh[kt], at, 0, 0, 0);
        }
        __builtin_amdgcn_s_setprio(0);

        // z1 += b1; merged ln_bwd stats (6 mu-independent sums) — intra-wave
        float c1g[4][4];
        float s1 = 0.f, s2 = 0.f, a1 = 0.f, a4 = 0.f, a3 = 0.f, a5 = 0.f;
#pragma unroll
        for (int jt = 0; jt < 4; jt++)
#pragma unroll
            for (int r = 0; r < 4; r++) {
                float z = z1[jt][r] + b1v[jt][r];
                z1[jt][r] = z;
                float t = xv[jt][r] - xkt[jt][r];
                c1g[jt][r] = (b4[jt][r] - t) * g4[jt][r];
                s1 += z; s2 += z * z;
                float gz = gg4[jt][r] * z;
                a1 += gz; a4 += gz * z;
                a3 += c1g[jt][r]; a5 += c1g[jt][r] * z;
            }
        s1 += __shfl_xor(s1, 16); s2 += __shfl_xor(s2, 16);
        a1 += __shfl_xor(a1, 16); a4 += __shfl_xor(a4, 16);
        a3 += __shfl_xor(a3, 16); a5 += __shfl_xor(a5, 16);
        s1 += __shfl_xor(s1, 32); s2 += __shfl_xor(s2, 32);
        a1 += __shfl_xor(a1, 32); a4 += __shfl_xor(a4, 32);
        a3 += __shfl_xor(a3, 32); a5 += __shfl_xor(a5, 32);

        float mu = s1 * (1.0f / 64.0f);
        float var = s2 * (1.0f / 64.0f) - mu * mu;
        float rstd = rsqrtf(var + EPS);
        float T1 = rstd * (a1 - mu * Ag2) + a3;
        float T2 = rstd * rstd * (a4 - 2.0f * mu * a1 + mu * mu * Ag2)
                 + rstd * (a5 - mu * a3);
        // grad_e -> sGE [m][j]
#pragma unroll
        for (int jt = 0; jt < 4; jt++) {
            i32x4 gw;
#pragma unroll
            for (int r = 0; r < 4; r++) {
                float xh = (z1[jt][r] - mu) * rstd;
                float gxh = gg4[jt][r] * xh + c1g[jt][r];
                float grad = (64.0f * gxh - T1 - xh * T2) * (rstd * (1.0f / 64.0f));
                gw[r] = (int)tpack(sc * grad);
            }
            *(i32x4*)&S->sGE[m16 * 68 + 16 * jt + quad * 4] = gw;
        }
        // -C' masked -> sCB [m][i]
        {
            i32x4 cw;
#pragma unroll
            for (int r = 0; r < 4; r++) {
                float v = (m16 <= quad * 4 + r) ? -(tki[r] * (1.0f + at[r])) : 0.0f;
                cw[r] = (int)tpack(v);
            }
            *(i32x4*)&S->sCB[m16 * 20 + quad * 4] = cw;
        }
        fence_lds();   // F1: XKp/GE/CB visible (also drains last step's sUw reads)

        // assemble grad / C' fragments (K=32, tokens in quads 0-1, zero pad)
        bf16x8 gh[4], gl[4], cbh, cbl;
#pragma unroll
        for (int jt = 0; jt < 4; jt++) {
#pragma unroll
            for (int e = 0; e < 8; e++) {
                unsigned u = (quad < 2) ? S->sGE[(quad * 8 + e) * 68 + 16 * jt + m16] : 0u;
                gh[jt][e] = (short)(u >> 16); gl[jt][e] = (short)(u & 0xffffu);
            }
        }
#pragma unroll
        for (int e = 0; e < 8; e++) {
            unsigned u = (quad < 2) ? S->sCB[(quad * 8 + e) * 20 + m16] : 0u;
            cbh[e] = (short)(u >> 16); cbl[e] = (short)(u & 0xffffu);
        }

        __builtin_amdgcn_s_setprio(1);
        // U = XK^T @ grad_e — 16 tiles -> sUw[j][k]
#pragma unroll
        for (int kr = 0; kr < 4; kr++) {
            bf16x8 akh8, akl8;
#pragma unroll
            for (int e = 0; e < 8; e++) {
                unsigned u = (quad < 2) ? S->sXKp[(quad * 8 + e) * 68 + 16 * kr + m16] : 0u;
                akh8[e] = (short)(u >> 16); akl8[e] = (short)(u & 0xffffu);
            }
#pragma unroll
            for (int jt = 0; jt < 4; jt++) {
                f32x4 ua = {0.f, 0.f, 0.f, 0.f};
                ua = __builtin_amdgcn_mfma_f32_16x16x32_bf16(akh8, gh[jt], ua, 0, 0, 0);
                ua = __builtin_amdgcn_mfma_f32_16x16x32_bf16(akl8, gh[jt], ua, 0, 0, 0);
                ua = __builtin_amdgcn_mfma_f32_16x16x32_bf16(akh8, gl[jt], ua, 0, 0, 0);
                *(f32x4*)&S->sUw[(16 * jt + m16) * 68 + 16 * kr + quad * 4] = ua;
            }
        }
        // ZQ correction + b1 decrement
#pragma unroll
        for (int jt = 0; jt < 4; jt++) {
            zq[jt] = __builtin_amdgcn_mfma_f32_16x16x32_bf16(gh[jt], cbh, zq[jt], 0, 0, 0);
            zq[jt] = __builtin_amdgcn_mfma_f32_16x16x32_bf16(gl[jt], cbh, zq[jt], 0, 0, 0);
            zq[jt] = __builtin_amdgcn_mfma_f32_16x16x32_bf16(gh[jt], cbl, zq[jt], 0, 0, 0);
            f32x4 bda = {0.f, 0.f, 0.f, 0.f};
            bda = __builtin_amdgcn_mfma_f32_16x16x32_bf16(ones8, gh[jt], bda, 0, 0, 0);
            bda = __builtin_amdgcn_mfma_f32_16x16x32_bf16(ones8, gl[jt], bda, 0, 0, 0);
            if (quad == 0) S->sB1d[16 * jt + m16] = bda[0];
        }
        __builtin_amdgcn_s_setprio(0);

        // zb = zq + b1(old); LN stats intra-wave; output
        float zb[4][4]; float u1 = 0.f, u2 = 0.f;
#pragma unroll
        for (int jt = 0; jt < 4; jt++)
#pragma unroll
            for (int r = 0; r < 4; r++) {
                float z = zq[jt][r] + b1v[jt][r];
                zb[jt][r] = z; u1 += z; u2 += z * z;
            }
        u1 += __shfl_xor(u1, 16); u2 += __shfl_xor(u2, 16);
        u1 += __shfl_xor(u1, 32); u2 += __shfl_xor(u2, 32);
        float mu2 = u1 * (1.0f / 64.0f);
        float va2 = u2 * (1.0f / 64.0f) - mu2 * mu2;
        float rs2 = rsqrtf(va2 + EPS);
#pragma unroll
        for (int jt = 0; jt < 4; jt++) {
            float4 ov;
            ov.x = (bfu2f(qoh[jt].x) + bfu2f(qol[jt].x)) + fmaf(g4[jt][0], (zb[jt][0] - mu2) * rs2, b4[jt][0]);
            ov.y = (bfu2f(qoh[jt].y) + bfu2f(qol[jt].y)) + fmaf(g4[jt][1], (zb[jt][1] - mu2) * rs2, b4[jt][1]);
            ov.z = (bfu2f(qoh[jt].z) + bfu2f(qol[jt].z)) + fmaf(g4[jt][2], (zb[jt][2] - mu2) * rs2, b4[jt][2]);
            ov.w = (bfu2f(qoh[jt].w) + bfu2f(qol[jt].w)) + fmaf(g4[jt][3], (zb[jt][3] - mu2) * rs2, b4[jt][3]);
            *(float4*)&outB[(size_t)(s * 16 + m16) * WIDTH + 16 * jt + quad * 4] = ov;
        }

        fence_lds();   // F2: sUw/sB1d visible (also drains XKp/GE/CB reads before next-step writes)

        // W1 -= U (readback at master positions); b1 -= sum(grad_e)
#pragma unroll
        for (int jt = 0; jt < 4; jt++) {
#pragma unroll
            for (int kt = 0; kt < 2; kt++) {
                f32x4 u0 = *(const f32x4*)&S->sUw[(16 * jt + m16) * 68 + 32 * kt + quad * 8];
                f32x4 u1v = *(const f32x4*)&S->sUw[(16 * jt + m16) * 68 + 32 * kt + quad * 8 + 4];
#pragma unroll
                for (int e = 0; e < 4; e++) {
                    float f = W1f[jt][kt][e] - u0[e];
                    W1f[jt][kt][e] = f;
                    unsigned short hh, ll; tsplit(f, hh, ll);
                    w1h[jt][kt][e] = (short)hh; w1l[jt][kt][e] = (short)ll;
                }
#pragma unroll
                for (int e = 0; e < 4; e++) {
                    float f = W1f[jt][kt][4 + e] - u1v[e];
                    W1f[jt][kt][4 + e] = f;
                    unsigned short hh, ll; tsplit(f, hh, ll);
                    w1h[jt][kt][4 + e] = (short)hh; w1l[jt][kt][4 + e] = (short)ll;
                }
            }
            float4 bdv = *(const float4*)&S->sB1d[16 * jt + quad * 4];
            b1v[jt][0] -= bdv.x; b1v[jt][1] -= bdv.y;
            b1v[jt][2] -= bdv.z; b1v[jt][3] -= bdv.w;
        }
    }
}

// ============ mega kernel: scan (48, 1 wave each) + wo transpose (144) + gate GEMM (768) ============
__global__ __launch_bounds__(256, 1)
void mega_kernel(const unsigned short* __restrict__ XQh, const unsigned short* __restrict__ XQl,
                 const unsigned short* __restrict__ XKh, const unsigned short* __restrict__ XKl,
                 const float* __restrict__ XVb, const float* __restrict__ lrbuf,
                 const float* __restrict__ W1, const float* __restrict__ b1,
                 const float* __restrict__ tns, const float* __restrict__ tnb,
                 const float* __restrict__ lti, float* __restrict__ ttto,
                 const float* __restrict__ wo, unsigned short* __restrict__ woThi,
                 unsigned short* __restrict__ woTlo,
                 const float* __restrict__ hidden, const unsigned short* __restrict__ wTgh,
                 const unsigned short* __restrict__ wTgl, float* __restrict__ gate)
{
    __shared__ __align__(16) char sm[SMEM_BYTES];
    int bid = blockIdx.x;
    if (bid < 48) {
        if (threadIdx.x < 64)
            scan_wave(sm, threadIdx.x, bid, XQh, XQl, XKh, XKl, XVb, lrbuf,
                      W1, b1, tns, tnb, lti, ttto);
        return;
    } else if (bid < 192) {
        int idx = bid - 48;
        wtconv_body(sm, threadIdx.x, (idx % 12) * 64, (idx / 12) * 64, wo, woThi, woTlo);
    } else {
        int idx = bid - 192;
        int bx = idx % 6, by = idx / 6;
        int bn = bx * 128;
        gemm_body<1, 1>(sm, threadIdx.x, by, hidden, nullptr, nullptr,
                        wTgh + (size_t)bn * WIDTH, wTgl + (size_t)bn * WIDTH,
                        gate + bn, WIDTH, WIDTH);
    }
}

// ---------------- standalone GEMM kernels ----------------
__global__ __launch_bounds__(256, 2)
void gemm_qv_kernel(const float* __restrict__ hidden,
                    const unsigned short* __restrict__ wThi, const unsigned short* __restrict__ wTlo,
                    float* __restrict__ xqk, float* __restrict__ XVb)
{
    __shared__ __align__(16) char sm[SMEM_BYTES];
    int bn = blockIdx.x * 128;
    float* C = (bn < WIDTH) ? (xqk + bn) : (XVb + bn - WIDTH);
    gemm_body<0, 1>(sm, threadIdx.x, blockIdx.y, hidden, nullptr, nullptr,
                    wThi + (size_t)bn * WIDTH, wTlo + (size_t)bn * WIDTH, C, WIDTH, WIDTH);
}

__global__ __launch_bounds__(256, 2)
void gemm_out_kernel(const unsigned short* __restrict__ gzh, const unsigned short* __restrict__ gzl,
                     const unsigned short* __restrict__ woThi, const unsigned short* __restrict__ woTlo,
                     float* __restrict__ out)
{
    __shared__ __align__(16) char sm[SMEM_BYTES];
    int bn = blockIdx.x * 128;
    gemm_body<0, 0>(sm, threadIdx.x, blockIdx.y, nullptr, gzh, gzl,
                    woThi + (size_t)bn * WIDTH, woTlo + (size_t)bn * WIDTH, out + bn, WIDTH, WIDTH);
}

// ---------------- transpose+split wq/wv/wg in one launch ----------------
__global__ __launch_bounds__(256)
void wtconv3_kernel(const float* __restrict__ wq, const float* __restrict__ wv,
                    const float* __restrict__ wg,
                    unsigned short* __restrict__ hiT, unsigned short* __restrict__ loT)
{
    __shared__ __align__(16) char sm[sizeof(WtSM)];
    int widx = blockIdx.z;
    const float* src = (widx == 0) ? wq : ((widx == 1) ? wv : wg);
    size_t off = (size_t)widx * WIDTH * WIDTH;
    wtconv_body(sm, threadIdx.x, blockIdx.x * 64, blockIdx.y * 64, src, hiT + off, loT + off);
}

// ------- causal dwconv (W=4) + RoPE; outputs hi/lo bf16 planes, per-head layout -------
__global__ __launch_bounds__(384)
void conv_rope_kernel(const float* __restrict__ xqk,
                      const float* __restrict__ kq, const float* __restrict__ bq,
                      const float* __restrict__ kk, const float* __restrict__ bk,
                      unsigned short* __restrict__ XQh, unsigned short* __restrict__ XQl,
                      unsigned short* __restrict__ XKh, unsigned short* __restrict__ XKl)
{
    int bid = blockIdx.x;        // b*4096 + n
    int n = bid & (NSEQ - 1);
    int b = bid >> 12;
    int p = threadIdx.x;         // pair 0..383
    int c = p * 2;
    int pp = p & 31;
    float qe = bq[c], qo = bq[c + 1], ke = bk[c], ko = bk[c + 1];
#pragma unroll
    for (int w = 0; w < 4; w++) {
        int nn = n - 3 + w;
        if (nn >= 0) {
            const float* xr = xqk + ((size_t)(bid - n + nn)) * WIDTH + c;
            float xe = xr[0], xo = xr[1];
            qe = fmaf(xe, kq[w * WIDTH + c], qe);
            qo = fmaf(xo, kq[w * WIDTH + c + 1], qo);
            ke = fmaf(xe, kk[w * WIDTH + c], ke);
            ko = fmaf(xo, kk[w * WIDTH + c + 1], ko);
        }
    }
    int pos = n & (MINI - 1);
    float freq = expf(-(float)pp * (9.210340371976184f / 32.0f));
    float ang = (float)pos * freq;
    float c_ = cosf(ang), s_ = sinf(ang);
    int hh = p >> 5;
    int cc = pp * 2;
    size_t o = ((size_t)(b * HEADS + hh) * NSEQ + n) * 64 + cc;
    float q0 = qe * c_ - qo * s_, q1 = qe * s_ + qo * c_;
    float k0 = ke * c_ - ko * s_, k1 = ke * s_ + ko * c_;
    ushort2 h2, l2;
    tsplit(q0, h2.x, l2.x); tsplit(q1, h2.y, l2.y);
    *(ushort2*)&XQh[o] = h2; *(ushort2*)&XQl[o] = l2;
    tsplit(k0, h2.x, l2.x); tsplit(k1, h2.y, l2.y);
    *(ushort2*)&XKh[o] = h2; *(ushort2*)&XKl[o] = l2;
}

// ---------------- per-(b,h,token) ttt_lr ----------------
__global__ __launch_bounds__(256)
void lr_kernel(const float* __restrict__ hidden, const float* __restrict__ lrk,
               const float* __restrict__ lrb, float* __restrict__ lr_buf)
{
    int wave = threadIdx.x >> 6;
    int lane = threadIdx.x & 63;
    int row = blockIdx.x * 4 + wave;
    int b = row >> 12;
    int n = row & (NSEQ - 1);
    const float* hr = hidden + (size_t)row * WIDTH;
    float hv[12];
#pragma unroll
    for (int t = 0; t < 12; t++) hv[t] = hr[lane + 64 * t];
    for (int h = 0; h < HEADS; h++) {
        const float* lk = lrk + h * WIDTH;
        float acc = 0.f;
#pragma unroll
        for (int t = 0; t < 12; t++) acc = fmaf(hv[t], lk[lane + 64 * t], acc);
#pragma unroll
        for (int m = 1; m < 64; m <<= 1) acc += __shfl_xor(acc, m);
        if (lane == 0) {
            float s = 1.0f / (1.0f + __expf(-(acc + lrb[h])));
            lr_buf[((size_t)(b * HEADS + h)) * NSEQ + n] = s * (1.0f / HD);
        }
    }
}

// ---------------- post-norm over 768 + gate multiply, emits hi/lo planes ----------------
__global__ __launch_bounds__(256)
void postgate_kernel(const float* __restrict__ tout, const float* __restrict__ gate,
                     const float* __restrict__ ps, const float* __restrict__ pb,
                     unsigned short* __restrict__ gzh, unsigned short* __restrict__ gzl)
{
    __shared__ float red[8];
    int row = blockIdx.x;
    int tid = threadIdx.x;
    const float* x = tout + (size_t)row * WIDTH;
    float v[3];
    float s1 = 0, s2 = 0;
#pragma unroll
    for (int t = 0; t < 3; t++) { v[t] = x[tid + 256 * t]; s1 += v[t]; s2 += v[t] * v[t]; }
#pragma unroll
    for (int m = 1; m < 64; m <<= 1) { s1 += __shfl_xor(s1, m); s2 += __shfl_xor(s2, m); }
    int wave = tid >> 6, lane = tid & 63;
    if (lane == 0) { red[wave] = s1; red[4 + wave] = s2; }
    __syncthreads();
    s1 = red[0] + red[1] + red[2] + red[3];
    s2 = red[4] + red[5] + red[6] + red[7];
    float mu = s1 * (1.0f / WIDTH);
    float var = s2 * (1.0f / WIDTH) - mu * mu;
    float rstd = rsqrtf(var + EPS);
#pragma unroll
    for (int t = 0; t < 3; t++) {
        int c = tid + 256 * t;
        float z = ps[c] * (v[t] - mu) * rstd + pb[c];
        float gv = gate[(size_t)row * WIDTH + c] * z;
        unsigned short hh, ll; tsplit(gv, hh, ll);
        gzh[(size_t)row * WIDTH + c] = hh;
        gzl[(size_t)row * WIDTH + c] = ll;
    }
}

extern "C" void kernel_launch(void* const* d_in, const int* in_sizes, int n_in,
                              void* d_out, int out_size, void* d_ws, size_t ws_size,
                              hipStream_t stream)
{
    (void)in_sizes; (void)n_in; (void)out_size; (void)ws_size;
    const float* hidden = (const float*)d_in[0];
    const float* wq  = (const float*)d_in[1];
    const float* wv  = (const float*)d_in[2];
    const float* wo  = (const float*)d_in[3];
    const float* wg  = (const float*)d_in[4];
    const float* ckq = (const float*)d_in[5];
    const float* cbq = (const float*)d_in[6];
    const float* ckk = (const float*)d_in[7];
    const float* cbk = (const float*)d_in[8];
    const float* W1  = (const float*)d_in[9];
    const float* b1  = (const float*)d_in[10];
    const float* tns = (const float*)d_in[11];
    const float* tnb = (const float*)d_in[12];
    const float* lrk = (const float*)d_in[13];
    const float* lrb = (const float*)d_in[14];
    const float* lti = (const float*)d_in[15];
    const float* pns = (const float*)d_in[16];
    const float* pnb = (const float*)d_in[17];
    float* out = (float*)d_out;

    const size_t BIG = (size_t)BATCH * NSEQ * WIDTH;   // 12.58M floats
    float* ws  = (float*)d_ws;
    float* xqk = ws;                                   // -> ttt_out (reused after conv_rope)
    float* XVb = ws + BIG;
    unsigned short* XQhi = (unsigned short*)(ws + 2 * BIG);
    unsigned short* XQlo = XQhi + BIG;
    unsigned short* XKhi = (unsigned short*)(ws + 3 * BIG);
    unsigned short* XKlo = XKhi + BIG;
    float* tail = ws + 4 * BIG;
    unsigned short* wThi  = (unsigned short*)tail;          // [2304][768]
    unsigned short* wTlo  = wThi + (size_t)2304 * WIDTH;
    unsigned short* woThi = wTlo + (size_t)2304 * WIDTH;    // [768][768]
    unsigned short* woTlo = woThi + (size_t)WIDTH * WIDTH;
    float* lrbuf = (float*)(woTlo + (size_t)WIDTH * WIDTH);
    unsigned short* gzhi = (unsigned short*)(ws + 2 * BIG); // reuse XQ planes post-scan
    unsigned short* gzlo = gzhi + BIG;
    float* gate = out;    // d_out as scratch until final GEMM
    float* ttto = xqk;

    int M = BATCH * NSEQ;
    wtconv3_kernel<<<dim3(12, 12, 3), 256, 0, stream>>>(wq, wv, wg, wThi, wTlo);
    gemm_qv_kernel<<<dim3(12, M / 128), 256, 0, stream>>>(hidden, wThi, wTlo, xqk, XVb);
    conv_rope_kernel<<<M, 384, 0, stream>>>(xqk, ckq, cbq, ckk, cbk, XQhi, XQlo, XKhi, XKlo);
    lr_kernel<<<M / 4, 256, 0, stream>>>(hidden, lrk, lrb, lrbuf);
    mega_kernel<<<960, 256, 0, stream>>>(XQhi, XQlo, XKhi, XKlo, XVb, lrbuf,
                                         W1, b1, tns, tnb, lti, ttto,
                                         wo, woThi, woTlo,
                                         hidden, wThi + (size_t)1536 * WIDTH,
                                         wTlo + (size_t)1536 * WIDTH, gate);
    postgate_kernel<<<M, 256, 0, stream>>>(ttto, gate, pns, pnb, gzhi, gzlo);
    gemm_out_kernel<<<dim3(6, M / 128), 256, 0, stream>>>(gzhi, gzlo, woThi, woTlo, out);
}

// Round 5
// 1077.307 us; speedup vs baseline: 1.4412x; 1.4412x over previous
//
#include <hip/hip_runtime.h>
#include <math.h>

#define WIDTH 768
#define HEADS 12
#define HD 64
#define MINI 16
#define NSEQ 4096
#define BATCH 4
#define NMB (NSEQ/MINI)
#define EPS 1e-6f

typedef __attribute__((ext_vector_type(8))) short bf16x8;
typedef __attribute__((ext_vector_type(4))) float f32x4;
typedef __attribute__((ext_vector_type(4))) int   i32x4;

__device__ __forceinline__ float bfu2f(unsigned short h) {
    return __uint_as_float(((unsigned)h) << 16);
}
// truncation-based split: f = hi + lo to ~2^-16 relative
__device__ __forceinline__ void tsplit(float f, unsigned short& h, unsigned short& l) {
    unsigned uh = __float_as_uint(f) & 0xffff0000u;
    h = (unsigned short)(uh >> 16);
    l = (unsigned short)(__float_as_uint(f - __uint_as_float(uh)) >> 16);
}
__device__ __forceinline__ unsigned tpack(float f) {
    unsigned uh = __float_as_uint(f) & 0xffff0000u;
    return uh | (__float_as_uint(f - __uint_as_float(uh)) >> 16);
}
// barrier that does NOT drain vmcnt: global prefetch stays in flight
__device__ __forceinline__ void barrier_lgkm() {
    asm volatile("s_waitcnt lgkmcnt(0)\n\ts_barrier" ::: "memory");
}
// wave-private LDS fence (rule 18: sched_barrier after inline-asm lgkmcnt)
__device__ __forceinline__ void fence_lds() {
    asm volatile("s_waitcnt lgkmcnt(0)" ::: "memory");
    __builtin_amdgcn_sched_barrier(0);
}

// ---------------- shared-memory overlays ----------------
struct ScanSM8 {                     // 45568 B
    unsigned sXKp[2][16 * 68];       // shared XK (packed hi|lo), [par][m][k], w0 writes
    unsigned sGE[4][16 * 20];        // wave-private grad_e, [w][m][j-in-tile]
    unsigned sCB[4][16 * 20];        // wave-private -C', [w][m][i]
    float    sUp[4][16 * 68];        // wave-private U, [w][j-in-tile(m16)][k] (b128 both sides)
    float    sRedM[2][16 * 36];      // 6-sum stats, parity-buffered
    float    sRed3[2][16 * 36];      // zb 2-sum stats, parity-buffered
};
struct GemmSM {
    unsigned short sAh[128 * 40], sAl[128 * 40];
    unsigned short sBh[128 * 40], sBl[128 * 40];
};
struct WtSM { float sT[64][65]; };
#define SMEM_BYTES 46080   // sizeof(ScanSM8)=45568 is the max

// ---------------- transpose + split weight tile: w[K][N] -> hiT/loT[N][K] ----------------
__device__ void wtconv_body(char* smraw, int tid, int n0, int k0, const float* __restrict__ w,
                            unsigned short* __restrict__ hiT, unsigned short* __restrict__ loT)
{
    WtSM* W = (WtSM*)smraw;
    int t = tid, r = t >> 2, cs = (t & 3) * 16;
#pragma unroll
    for (int i = 0; i < 16; i += 4)
        *(float4*)&W->sT[r][cs + i] = *(const float4*)&w[(size_t)(k0 + r) * WIDTH + n0 + cs + i];
    __syncthreads();
    ushort4 hb[4], lb[4];
#pragma unroll
    for (int i = 0; i < 16; i++) {
        unsigned short hh, ll;
        tsplit(W->sT[cs + i][r], hh, ll);
        ((unsigned short*)hb)[i] = hh;
        ((unsigned short*)lb)[i] = ll;
    }
#pragma unroll
    for (int i = 0; i < 4; i++) {
        *(ushort4*)&hiT[(size_t)(n0 + r) * WIDTH + k0 + cs + i * 4] = hb[i];
        *(ushort4*)&loT[(size_t)(n0 + r) * WIDTH + k0 + cs + i * 4] = lb[i];
    }
}

// ---------------- split-bf16 3-term MFMA GEMM body (256 thr, 128x128) ----------------
template<int ACT, int SPLITA>
__device__ void gemm_body(char* smraw, int tid, int by,
                          const float* __restrict__ Af,
                          const unsigned short* __restrict__ APh,
                          const unsigned short* __restrict__ APl,
                          const unsigned short* __restrict__ BhT,
                          const unsigned short* __restrict__ BlT,
                          float* __restrict__ C, int ldc, int K)
{
    GemmSM* g = (GemmSM*)smraw;
    const int bm = by * 128;
    const int w = tid >> 6, lane = tid & 63, quad = lane >> 4, m16 = lane & 15;
    const int mw = (w & 1) * 64, nw = (w >> 1) * 64;
    const int srow = tid >> 1, sseg = (tid & 1) * 16;
    f32x4 acc[4][4];
#pragma unroll
    for (int a = 0; a < 4; a++)
#pragma unroll
        for (int c = 0; c < 4; c++) acc[a][c] = (f32x4){0.f, 0.f, 0.f, 0.f};

    for (int k0 = 0; k0 < K; k0 += 32) {
        uint4 vb0 = *(const uint4*)(BhT + (size_t)srow * K + k0 + sseg);
        uint4 vb1 = *(const uint4*)(BhT + (size_t)srow * K + k0 + sseg + 8);
        uint4 vd0 = *(const uint4*)(BlT + (size_t)srow * K + k0 + sseg);
        uint4 vd1 = *(const uint4*)(BlT + (size_t)srow * K + k0 + sseg + 8);
        if (SPLITA) {
            const float* Ap = Af + (size_t)(bm + srow) * K + k0 + sseg;
            float4 f0 = *(const float4*)(Ap);
            float4 f1 = *(const float4*)(Ap + 4);
            float4 f2 = *(const float4*)(Ap + 8);
            float4 f3 = *(const float4*)(Ap + 12);
            __syncthreads();
            unsigned short hs[16], ls[16];
            float fv[16] = {f0.x, f0.y, f0.z, f0.w, f1.x, f1.y, f1.z, f1.w,
                            f2.x, f2.y, f2.z, f2.w, f3.x, f3.y, f3.z, f3.w};
#pragma unroll
            for (int i = 0; i < 16; i++) tsplit(fv[i], hs[i], ls[i]);
            *(uint4*)&g->sAh[srow * 40 + sseg]     = *(uint4*)&hs[0];
            *(uint4*)&g->sAh[srow * 40 + sseg + 8] = *(uint4*)&hs[8];
            *(uint4*)&g->sAl[srow * 40 + sseg]     = *(uint4*)&ls[0];
            *(uint4*)&g->sAl[srow * 40 + sseg + 8] = *(uint4*)&ls[8];
        } else {
            uint4 va0 = *(const uint4*)(APh + (size_t)(bm + srow) * K + k0 + sseg);
            uint4 va1 = *(const uint4*)(APh + (size_t)(bm + srow) * K + k0 + sseg + 8);
            uint4 vc0 = *(const uint4*)(APl + (size_t)(bm + srow) * K + k0 + sseg);
            uint4 vc1 = *(const uint4*)(APl + (size_t)(bm + srow) * K + k0 + sseg + 8);
            __syncthreads();
            *(uint4*)&g->sAh[srow * 40 + sseg] = va0; *(uint4*)&g->sAh[srow * 40 + sseg + 8] = va1;
            *(uint4*)&g->sAl[srow * 40 + sseg] = vc0; *(uint4*)&g->sAl[srow * 40 + sseg + 8] = vc1;
        }
        *(uint4*)&g->sBh[srow * 40 + sseg] = vb0; *(uint4*)&g->sBh[srow * 40 + sseg + 8] = vb1;
        *(uint4*)&g->sBl[srow * 40 + sseg] = vd0; *(uint4*)&g->sBl[srow * 40 + sseg + 8] = vd1;
        __syncthreads();
        bf16x8 ah[4], al[4];
#pragma unroll
        for (int mt = 0; mt < 4; mt++) {
            ah[mt] = *(const bf16x8*)&g->sAh[(mw + mt * 16 + m16) * 40 + quad * 8];
            al[mt] = *(const bf16x8*)&g->sAl[(mw + mt * 16 + m16) * 40 + quad * 8];
        }
#pragma unroll
        for (int nt = 0; nt < 4; nt++) {
            bf16x8 bh8 = *(const bf16x8*)&g->sBh[(nw + nt * 16 + m16) * 40 + quad * 8];
            bf16x8 bl8 = *(const bf16x8*)&g->sBl[(nw + nt * 16 + m16) * 40 + quad * 8];
#pragma unroll
            for (int mt = 0; mt < 4; mt++) {
                acc[mt][nt] = __builtin_amdgcn_mfma_f32_16x16x32_bf16(ah[mt], bh8, acc[mt][nt], 0, 0, 0);
                acc[mt][nt] = __builtin_amdgcn_mfma_f32_16x16x32_bf16(al[mt], bh8, acc[mt][nt], 0, 0, 0);
                acc[mt][nt] = __builtin_amdgcn_mfma_f32_16x16x32_bf16(ah[mt], bl8, acc[mt][nt], 0, 0, 0);
            }
        }
    }
#pragma unroll
    for (int mt = 0; mt < 4; mt++)
#pragma unroll
        for (int nt = 0; nt < 4; nt++)
#pragma unroll
            for (int r = 0; r < 4; r++) {
                float v = acc[mt][nt][r];
                if (ACT == 1) {
                    float inner = 0.7978845608028654f * (v + 0.044715f * v * v * v);
                    v = 0.5f * v * (1.0f + tanhf(inner));
                }
                C[(size_t)(bm + mw + mt * 16 + quad * 4 + r) * ldc + nw + nt * 16 + m16] = v;
            }
}

// ============ TTT scan v9: 4 symmetric waves, ONE barrier/step ============
// Wave w owns j-tile w END-TO-END: Z1/ZQ (its j), grad (its j), U columns (its j, all k),
// W1 tile (its j), output (its j). Cross-wave traffic = the two LN stat reductions only.
// sGE/sCB/sUp are wave-private (lgkm fences); sXKp shared via B1 (parity-buffered);
// zb stats ride the NEXT step's B1 (deferred output, flushed one step late).
__device__ void scan_body(char* smraw, int tid, int bh,
    const unsigned short* __restrict__ XQh, const unsigned short* __restrict__ XQl,
    const unsigned short* __restrict__ XKh, const unsigned short* __restrict__ XKl,
    const float* __restrict__ XVb, const float* __restrict__ lr_buf,
    const float* __restrict__ W1g, const float* __restrict__ b1g,
    const float* __restrict__ gln, const float* __restrict__ blnv,
    const float* __restrict__ lti, float* __restrict__ out)
{
    ScanSM8* S = (ScanSM8*)smraw;
    const int w = tid >> 6, lane = tid & 63;
    const int quad = lane >> 4, m16 = lane & 15;
    const int b = bh / HEADS, h = bh - b * HEADS;
    const int jc = 16 * w + m16;         // W1/U column j per lane
    const int j4 = 16 * w + quad * 4;    // j row-block base

    float g4[4], b4[4], b1v[4], gg4[4];
#pragma unroll
    for (int r = 0; r < 4; r++) {
        g4[r] = gln[h * 64 + j4 + r];
        b4[r] = blnv[h * 64 + j4 + r];
        b1v[r] = b1g[h * 64 + j4 + r];
        gg4[r] = g4[r] * g4[r];
    }
    const float tok15 = fmaxf(1.0f / 16.0f + lti[15], 0.0f);
    float tki[4];   // all waves (symmetric Attn/C')
#pragma unroll
    for (int r = 0; r < 4; r++)
        tki[r] = fmaxf(1.0f / (float)(quad * 4 + r + 1) + lti[quad * 4 + r], 0.0f) / tok15;

    // Ag2 = sum_j g_j^2 (constant): via sRedM[1] scratch, double barrier (prologue only)
    float ags = (gg4[0] + gg4[1]) + (gg4[2] + gg4[3]);
    ags += __shfl_xor(ags, 16); ags += __shfl_xor(ags, 32);
    if (lane == 0) S->sRedM[1][w] = ags;
    barrier_lgkm();
    const float Ag2 = S->sRedM[1][0] + S->sRedM[1][1] + S->sRedM[1][2] + S->sRedM[1][3];
    barrier_lgkm();   // reads drained before loop's parity-1 writes

    // W1 master fp32 at B-frag positions [k=kt*32+quad*8+e][j=jc]
    float W1f[2][8]; bf16x8 w1h[2], w1l[2];
#pragma unroll
    for (int kt = 0; kt < 2; kt++)
#pragma unroll
        for (int e = 0; e < 8; e++) {
            float f = W1g[h * 4096 + (kt * 32 + quad * 8 + e) * 64 + jc];
            W1f[kt][e] = f;
            unsigned short hh, ll; tsplit(f, hh, ll);
            w1h[kt][e] = (short)hh; w1l[kt][e] = (short)ll;
        }

    const unsigned short* xqh = XQh + (size_t)bh * NSEQ * 64;
    const unsigned short* xql = XQl + (size_t)bh * NSEQ * 64;
    const unsigned short* xkh = XKh + (size_t)bh * NSEQ * 64;
    const unsigned short* xkl = XKl + (size_t)bh * NSEQ * 64;
    const float* xvB = XVb + (size_t)b * NSEQ * WIDTH + h * 64;
    const float* lrB = lr_buf + (size_t)bh * NSEQ;
    float* outB = out + (size_t)b * NSEQ * WIDTH + h * 64;

    bf16x8 ones8;
#pragma unroll
    for (int e = 0; e < 8; e++) ones8[e] = (short)0x3F80;
    const bf16x8 zf = {0, 0, 0, 0, 0, 0, 0, 0};

    // prefetch step 0
    bf16x8 pqh[2], pql[2], pkh[2], pkl[2];
    float4 pxv; ushort4 pth, ptl, poh, pol; float plr;
    {
        const size_t tok = m16;
#pragma unroll
        for (int kt = 0; kt < 2; kt++) {
            pqh[kt] = *(const bf16x8*)(xqh + tok * 64 + kt * 32 + quad * 8);
            pql[kt] = *(const bf16x8*)(xql + tok * 64 + kt * 32 + quad * 8);
            pkh[kt] = *(const bf16x8*)(xkh + tok * 64 + kt * 32 + quad * 8);
            pkl[kt] = *(const bf16x8*)(xkl + tok * 64 + kt * 32 + quad * 8);
        }
        pxv = *(const float4*)(xvB + tok * WIDTH + j4);
        pth = *(const ushort4*)(xkh + tok * 64 + j4);
        ptl = *(const ushort4*)(xkl + tok * 64 + j4);
        poh = *(const ushort4*)(xqh + tok * 64 + j4);
        pol = *(const ushort4*)(xql + tok * 64 + j4);
        plr = lrB[m16];
    }

    float dz[4] = {0.f, 0.f, 0.f, 0.f};   // deferred zb of previous step
    float dxq[4] = {0.f, 0.f, 0.f, 0.f};  // deferred XQ residual of previous step

    for (int s = 0; s < NMB; s++) {
        const int par = s & 1;
        bf16x8 qh[2] = {pqh[0], pqh[1]}, ql[2] = {pql[0], pql[1]};
        bf16x8 kh[2] = {pkh[0], pkh[1]}, kl[2] = {pkl[0], pkl[1]};
        float xv4[4] = {pxv.x, pxv.y, pxv.z, pxv.w};
        float xkt4[4], xqo4[4];
        xkt4[0] = bfu2f(pth.x) + bfu2f(ptl.x); xkt4[1] = bfu2f(pth.y) + bfu2f(ptl.y);
        xkt4[2] = bfu2f(pth.z) + bfu2f(ptl.z); xkt4[3] = bfu2f(pth.w) + bfu2f(ptl.w);
        xqo4[0] = bfu2f(poh.x) + bfu2f(pol.x); xqo4[1] = bfu2f(poh.y) + bfu2f(pol.y);
        xqo4[2] = bfu2f(poh.z) + bfu2f(pol.z); xqo4[3] = bfu2f(poh.w) + bfu2f(pol.w);
        const float sc = tok15 * plr;

        // stage shared sXKp[par] (w0 only; all waves hold identical kh/kl)
        if (w == 0) {
#pragma unroll
            for (int kt = 0; kt < 2; kt++) {
                i32x4 p0, p1;
#pragma unroll
                for (int e = 0; e < 4; e++)
                    p0[e] = (int)((((unsigned)(unsigned short)kh[kt][e]) << 16) | (unsigned short)kl[kt][e]);
#pragma unroll
                for (int e = 0; e < 4; e++)
                    p1[e] = (int)((((unsigned)(unsigned short)kh[kt][4 + e]) << 16) | (unsigned short)kl[kt][4 + e]);
                *(i32x4*)&S->sXKp[par][m16 * 68 + kt * 32 + quad * 8] = p0;
                *(i32x4*)&S->sXKp[par][m16 * 68 + kt * 32 + quad * 8 + 4] = p1;
            }
        }

        // prefetch next step (stays in flight across the lgkm-only barrier)
        {
            const int sn = (s + 1 < NMB) ? s + 1 : s;
            const size_t tok = (size_t)sn * 16 + m16;
#pragma unroll
            for (int kt = 0; kt < 2; kt++) {
                pqh[kt] = *(const bf16x8*)(xqh + tok * 64 + kt * 32 + quad * 8);
                pql[kt] = *(const bf16x8*)(xql + tok * 64 + kt * 32 + quad * 8);
                pkh[kt] = *(const bf16x8*)(xkh + tok * 64 + kt * 32 + quad * 8);
                pkl[kt] = *(const bf16x8*)(xkl + tok * 64 + kt * 32 + quad * 8);
            }
            pxv = *(const float4*)(xvB + tok * WIDTH + j4);
            pth = *(const ushort4*)(xkh + tok * 64 + j4);
            ptl = *(const ushort4*)(xkl + tok * 64 + j4);
            poh = *(const ushort4*)(xqh + tok * 64 + j4);
            pol = *(const ushort4*)(xql + tok * 64 + j4);
            plr = lrB[(size_t)sn * 16 + m16];
        }

        // phase 1: Z1^T, ZQ^T, Attn — symmetric on all waves
        f32x4 z1 = {0.f, 0.f, 0.f, 0.f}, zq = {0.f, 0.f, 0.f, 0.f}, at = {0.f, 0.f, 0.f, 0.f};
        __builtin_amdgcn_s_setprio(1);
#pragma unroll
        for (int kt = 0; kt < 2; kt++) {
            z1 = __builtin_amdgcn_mfma_f32_16x16x32_bf16(w1h[kt], kh[kt], z1, 0, 0, 0);
            z1 = __builtin_amdgcn_mfma_f32_16x16x32_bf16(w1h[kt], kl[kt], z1, 0, 0, 0);
            z1 = __builtin_amdgcn_mfma_f32_16x16x32_bf16(w1l[kt], kh[kt], z1, 0, 0, 0);
            zq = __builtin_amdgcn_mfma_f32_16x16x32_bf16(w1h[kt], qh[kt], zq, 0, 0, 0);
            zq = __builtin_amdgcn_mfma_f32_16x16x32_bf16(w1h[kt], ql[kt], zq, 0, 0, 0);
            zq = __builtin_amdgcn_mfma_f32_16x16x32_bf16(w1l[kt], qh[kt], zq, 0, 0, 0);
            at = __builtin_amdgcn_mfma_f32_16x16x32_bf16(qh[kt], kh[kt], at, 0, 0, 0);
            at = __builtin_amdgcn_mfma_f32_16x16x32_bf16(qh[kt], kl[kt], at, 0, 0, 0);
            at = __builtin_amdgcn_mfma_f32_16x16x32_bf16(ql[kt], kh[kt], at, 0, 0, 0);
        }
        __builtin_amdgcn_s_setprio(0);
#pragma unroll
        for (int r = 0; r < 4; r++) z1[r] += b1v[r];

        // merged ln_bwd stats: 6 mu-independent sums
        float c1g[4];
        float s1 = 0.f, s2 = 0.f, a1 = 0.f, a4 = 0.f, a3 = 0.f, a5 = 0.f;
#pragma unroll
        for (int r = 0; r < 4; r++) {
            float z = z1[r];
            float t = xv4[r] - xkt4[r];
            c1g[r] = (b4[r] - t) * g4[r];
            s1 += z; s2 += z * z;
            float gz = gg4[r] * z;
            a1 += gz; a4 += gz * z;
            a3 += c1g[r]; a5 += c1g[r] * z;
        }
        s1 += __shfl_xor(s1, 16); s2 += __shfl_xor(s2, 16);
        a1 += __shfl_xor(a1, 16); a4 += __shfl_xor(a4, 16);
        a3 += __shfl_xor(a3, 16); a5 += __shfl_xor(a5, 16);
        s1 += __shfl_xor(s1, 32); s2 += __shfl_xor(s2, 32);
        a1 += __shfl_xor(a1, 32); a4 += __shfl_xor(a4, 32);
        a3 += __shfl_xor(a3, 32); a5 += __shfl_xor(a5, 32);
        if (quad == 0) {
            *(float4*)&S->sRedM[par][m16 * 36 + w * 8]     = make_float4(s1, s2, a1, a4);
            *(float4*)&S->sRedM[par][m16 * 36 + w * 8 + 4] = make_float4(a3, a5, 0.f, 0.f);
        }
        // -C' masked, packed [m][i] — wave-private copy (every wave)
        {
            i32x4 cw;
#pragma unroll
            for (int r = 0; r < 4; r++) {
                float v = (m16 <= quad * 4 + r) ? -(tki[r] * (1.0f + at[r])) : 0.0f;
                cw[r] = (int)tpack(v);
            }
            *(i32x4*)&S->sCB[w][m16 * 20 + quad * 4] = cw;
        }
        barrier_lgkm();   // B1 — the only barrier per step

        // flush previous step's output (zb stats written before B1 by all waves)
        if (s > 0) {
            const int pp = par ^ 1;
            float V1 = 0.f, V2 = 0.f;
#pragma unroll
            for (int w2 = 0; w2 < 4; w2++) {
                float2 p = *(const float2*)&S->sRed3[pp][m16 * 36 + w2 * 8];
                V1 += p.x; V2 += p.y;
            }
            float mu2 = V1 * (1.0f / 64.0f);
            float va2 = V2 * (1.0f / 64.0f) - mu2 * mu2;
            float rs2 = rsqrtf(va2 + EPS);
            float4 ov;
            ov.x = dxq[0] + fmaf(g4[0], (dz[0] - mu2) * rs2, b4[0]);
            ov.y = dxq[1] + fmaf(g4[1], (dz[1] - mu2) * rs2, b4[1]);
            ov.z = dxq[2] + fmaf(g4[2], (dz[2] - mu2) * rs2, b4[2]);
            ov.w = dxq[3] + fmaf(g4[3], (dz[3] - mu2) * rs2, b4[3]);
            *(float4*)&outB[(size_t)((s - 1) * 16 + m16) * WIDTH + j4] = ov;
        }

        // cross-wave stats; grad for OWN j-tile -> private sGE
        float S1 = 0.f, S2 = 0.f, A1 = 0.f, A4 = 0.f, A3 = 0.f, A5 = 0.f;
#pragma unroll
        for (int w2 = 0; w2 < 4; w2++) {
            float4 pa = *(const float4*)&S->sRedM[par][m16 * 36 + w2 * 8];
            float4 pb = *(const float4*)&S->sRedM[par][m16 * 36 + w2 * 8 + 4];
            S1 += pa.x; S2 += pa.y; A1 += pa.z; A4 += pa.w;
            A3 += pb.x; A5 += pb.y;
        }
        float mu = S1 * (1.0f / 64.0f);
        float var = S2 * (1.0f / 64.0f) - mu * mu;
        float rstd = rsqrtf(var + EPS);
        float T1 = rstd * (A1 - mu * Ag2) + A3;
        float T2 = rstd * rstd * (A4 - 2.0f * mu * A1 + mu * mu * Ag2)
                 + rstd * (A5 - mu * A3);
        i32x4 gw;
#pragma unroll
        for (int r = 0; r < 4; r++) {
            float xh = (z1[r] - mu) * rstd;
            float gxh = gg4[r] * xh + c1g[r];
            float grad = (64.0f * gxh - T1 - xh * T2) * (rstd * (1.0f / 64.0f));
            gw[r] = (int)tpack(sc * grad);
        }
        *(i32x4*)&S->sGE[w][m16 * 20 + quad * 4] = gw;
        fence_lds();   // F1: private sGE/sCB writes visible to own wave

        // assemble fragments (K=32, tokens in quads 0-1, zero pad)
        bf16x8 gh = zf, gl = zf, cbh = zf, cbl = zf;
#pragma unroll
        for (int e = 0; e < 8; e++) {
            unsigned u = (quad < 2) ? S->sGE[w][(quad * 8 + e) * 20 + m16] : 0u;
            gh[e] = (short)(u >> 16); gl[e] = (short)(u & 0xffffu);
        }
#pragma unroll
        for (int e = 0; e < 8; e++) {
            unsigned u = (quad < 2) ? S->sCB[w][(quad * 8 + e) * 20 + m16] : 0u;
            cbh[e] = (short)(u >> 16); cbl[e] = (short)(u & 0xffffu);
        }

        __builtin_amdgcn_s_setprio(1);
        // U columns for OWN j-tile, all 4 k-row tiles -> private sUp[w][m16][k]
#pragma unroll
        for (int kr = 0; kr < 4; kr++) {
            bf16x8 akh8 = zf, akl8 = zf;
#pragma unroll
            for (int e = 0; e < 8; e++) {
                unsigned u = (quad < 2) ? S->sXKp[par][(quad * 8 + e) * 68 + 16 * kr + m16] : 0u;
                akh8[e] = (short)(u >> 16); akl8[e] = (short)(u & 0xffffu);
            }
            f32x4 ua = {0.f, 0.f, 0.f, 0.f};
            ua = __builtin_amdgcn_mfma_f32_16x16x32_bf16(akh8, gh, ua, 0, 0, 0);
            ua = __builtin_amdgcn_mfma_f32_16x16x32_bf16(akl8, gh, ua, 0, 0, 0);
            ua = __builtin_amdgcn_mfma_f32_16x16x32_bf16(akh8, gl, ua, 0, 0, 0);
            *(f32x4*)&S->sUp[w][m16 * 68 + 16 * kr + 4 * quad] = ua;
        }
        // ZQ correction (A = own grad frag, B = C')
        zq = __builtin_amdgcn_mfma_f32_16x16x32_bf16(gh, cbh, zq, 0, 0, 0);
        zq = __builtin_amdgcn_mfma_f32_16x16x32_bf16(gl, cbh, zq, 0, 0, 0);
        zq = __builtin_amdgcn_mfma_f32_16x16x32_bf16(gh, cbl, zq, 0, 0, 0);
        // b1 decrement for own j-tile (colsums of grad_e)
        f32x4 bda = {0.f, 0.f, 0.f, 0.f};
        bda = __builtin_amdgcn_mfma_f32_16x16x32_bf16(ones8, gh, bda, 0, 0, 0);
        bda = __builtin_amdgcn_mfma_f32_16x16x32_bf16(ones8, gl, bda, 0, 0, 0);
        __builtin_amdgcn_s_setprio(0);
        float bd[4];
#pragma unroll
        for (int r = 0; r < 4; r++)
            bd[r] = __shfl(bda[0], quad * 16 + quad * 4 + r);   // colsum[j=16w+4q+r]

        // zb = zq + b1(old); partial 2-sums -> sRed3[par] (read after NEXT B1)
        float zb[4]; float u1 = 0.f, u2 = 0.f;
#pragma unroll
        for (int r = 0; r < 4; r++) {
            float z = zq[r] + b1v[r];
            zb[r] = z; u1 += z; u2 += z * z;
        }
        u1 += __shfl_xor(u1, 16); u2 += __shfl_xor(u2, 16);
        u1 += __shfl_xor(u1, 32); u2 += __shfl_xor(u2, 32);
        if (quad == 0) *(float2*)&S->sRed3[par][m16 * 36 + w * 8] = make_float2(u1, u2);
#pragma unroll
        for (int r = 0; r < 4; r++) { dz[r] = zb[r]; dxq[r] = xqo4[r]; }
        fence_lds();   // F2: private sUp writes visible

        // W1 -= U (b128 readback, own tile); b1 -= colsum(grad_e)
#pragma unroll
        for (int kt = 0; kt < 2; kt++) {
            f32x4 u0 = *(const f32x4*)&S->sUp[w][m16 * 68 + 32 * kt + 8 * quad];
            f32x4 u1v = *(const f32x4*)&S->sUp[w][m16 * 68 + 32 * kt + 8 * quad + 4];
#pragma unroll
            for (int e = 0; e < 4; e++) {
                float f = W1f[kt][e] - u0[e];
                W1f[kt][e] = f;
                unsigned short hh, ll; tsplit(f, hh, ll);
                w1h[kt][e] = (short)hh; w1l[kt][e] = (short)ll;
            }
#pragma unroll
            for (int e = 0; e < 4; e++) {
                float f = W1f[kt][4 + e] - u1v[e];
                W1f[kt][4 + e] = f;
                unsigned short hh, ll; tsplit(f, hh, ll);
                w1h[kt][4 + e] = (short)hh; w1l[kt][4 + e] = (short)ll;
            }
        }
        b1v[0] -= bd[0]; b1v[1] -= bd[1]; b1v[2] -= bd[2]; b1v[3] -= bd[3];
    }

    // epilogue: flush the last step's output
    barrier_lgkm();
    {
        const int pp = (NMB - 1) & 1;
        float V1 = 0.f, V2 = 0.f;
#pragma unroll
        for (int w2 = 0; w2 < 4; w2++) {
            float2 p = *(const float2*)&S->sRed3[pp][m16 * 36 + w2 * 8];
            V1 += p.x; V2 += p.y;
        }
        float mu2 = V1 * (1.0f / 64.0f);
        float va2 = V2 * (1.0f / 64.0f) - mu2 * mu2;
        float rs2 = rsqrtf(va2 + EPS);
        float4 ov;
        ov.x = dxq[0] + fmaf(g4[0], (dz[0] - mu2) * rs2, b4[0]);
        ov.y = dxq[1] + fmaf(g4[1], (dz[1] - mu2) * rs2, b4[1]);
        ov.z = dxq[2] + fmaf(g4[2], (dz[2] - mu2) * rs2, b4[2]);
        ov.w = dxq[3] + fmaf(g4[3], (dz[3] - mu2) * rs2, b4[3]);
        *(float4*)&outB[(size_t)((NMB - 1) * 16 + m16) * WIDTH + j4] = ov;
    }
}

// ============ mega kernel: scan (48) + wo transpose (144) + gate GEMM (768) ============
__global__ __launch_bounds__(256, 2)
void mega_kernel(const unsigned short* __restrict__ XQh, const unsigned short* __restrict__ XQl,
                 const unsigned short* __restrict__ XKh, const unsigned short* __restrict__ XKl,
                 const float* __restrict__ XVb, const float* __restrict__ lrbuf,
                 const float* __restrict__ W1, const float* __restrict__ b1,
                 const float* __restrict__ tns, const float* __restrict__ tnb,
                 const float* __restrict__ lti, float* __restrict__ ttto,
                 const float* __restrict__ wo, unsigned short* __restrict__ woThi,
                 unsigned short* __restrict__ woTlo,
                 const float* __restrict__ hidden, const unsigned short* __restrict__ wTgh,
                 const unsigned short* __restrict__ wTgl, float* __restrict__ gate)
{
    __shared__ __align__(16) char sm[SMEM_BYTES];
    int bid = blockIdx.x;
    if (bid < 48) {
        scan_body(sm, threadIdx.x, bid, XQh, XQl, XKh, XKl, XVb, lrbuf, W1, b1, tns, tnb, lti, ttto);
    } else if (bid < 192) {
        int idx = bid - 48;
        wtconv_body(sm, threadIdx.x, (idx % 12) * 64, (idx / 12) * 64, wo, woThi, woTlo);
    } else {
        int idx = bid - 192;
        int bx = idx % 6, by = idx / 6;
        int bn = bx * 128;
        gemm_body<1, 1>(sm, threadIdx.x, by, hidden, nullptr, nullptr,
                        wTgh + (size_t)bn * WIDTH, wTgl + (size_t)bn * WIDTH,
                        gate + bn, WIDTH, WIDTH);
    }
}

// ---------------- standalone GEMM kernels ----------------
__global__ __launch_bounds__(256, 2)
void gemm_qv_kernel(const float* __restrict__ hidden,
                    const unsigned short* __restrict__ wThi, const unsigned short* __restrict__ wTlo,
                    float* __restrict__ xqk, float* __restrict__ XVb)
{
    __shared__ __align__(16) char sm[sizeof(GemmSM)];
    int bn = blockIdx.x * 128;
    float* C = (bn < WIDTH) ? (xqk + bn) : (XVb + bn - WIDTH);
    gemm_body<0, 1>(sm, threadIdx.x, blockIdx.y, hidden, nullptr, nullptr,
                    wThi + (size_t)bn * WIDTH, wTlo + (size_t)bn * WIDTH, C, WIDTH, WIDTH);
}

__global__ __launch_bounds__(256, 2)
void gemm_out_kernel(const unsigned short* __restrict__ gzh, const unsigned short* __restrict__ gzl,
                     const unsigned short* __restrict__ woThi, const unsigned short* __restrict__ woTlo,
                     float* __restrict__ out)
{
    __shared__ __align__(16) char sm[sizeof(GemmSM)];
    int bn = blockIdx.x * 128;
    gemm_body<0, 0>(sm, threadIdx.x, blockIdx.y, nullptr, gzh, gzl,
                    woThi + (size_t)bn * WIDTH, woTlo + (size_t)bn * WIDTH, out + bn, WIDTH, WIDTH);
}

// ---------------- transpose+split wq/wv/wg in one launch ----------------
__global__ __launch_bounds__(256)
void wtconv3_kernel(const float* __restrict__ wq, const float* __restrict__ wv,
                    const float* __restrict__ wg,
                    unsigned short* __restrict__ hiT, unsigned short* __restrict__ loT)
{
    __shared__ __align__(16) char sm[sizeof(WtSM)];
    int widx = blockIdx.z;
    const float* src = (widx == 0) ? wq : ((widx == 1) ? wv : wg);
    size_t off = (size_t)widx * WIDTH * WIDTH;
    wtconv_body(sm, threadIdx.x, blockIdx.x * 64, blockIdx.y * 64, src, hiT + off, loT + off);
}

// ------- causal dwconv (W=4) + RoPE; outputs hi/lo bf16 planes, per-head layout -------
__global__ __launch_bounds__(384)
void conv_rope_kernel(const float* __restrict__ xqk,
                      const float* __restrict__ kq, const float* __restrict__ bq,
                      const float* __restrict__ kk, const float* __restrict__ bk,
                      unsigned short* __restrict__ XQh, unsigned short* __restrict__ XQl,
                      unsigned short* __restrict__ XKh, unsigned short* __restrict__ XKl)
{
    int bid = blockIdx.x;        // b*4096 + n
    int n = bid & (NSEQ - 1);
    int b = bid >> 12;
    int p = threadIdx.x;         // pair 0..383
    int c = p * 2;
    int pp = p & 31;
    float qe = bq[c], qo = bq[c + 1], ke = bk[c], ko = bk[c + 1];
#pragma unroll
    for (int w = 0; w < 4; w++) {
        int nn = n - 3 + w;
        if (nn >= 0) {
            const float* xr = xqk + ((size_t)(bid - n + nn)) * WIDTH + c;
            float xe = xr[0], xo = xr[1];
            qe = fmaf(xe, kq[w * WIDTH + c], qe);
            qo = fmaf(xo, kq[w * WIDTH + c + 1], qo);
            ke = fmaf(xe, kk[w * WIDTH + c], ke);
            ko = fmaf(xo, kk[w * WIDTH + c + 1], ko);
        }
    }
    int pos = n & (MINI - 1);
    float freq = expf(-(float)pp * (9.210340371976184f / 32.0f));
    float ang = (float)pos * freq;
    float c_ = cosf(ang), s_ = sinf(ang);
    int hh = p >> 5;
    int cc = pp * 2;
    size_t o = ((size_t)(b * HEADS + hh) * NSEQ + n) * 64 + cc;
    float q0 = qe * c_ - qo * s_, q1 = qe * s_ + qo * c_;
    float k0 = ke * c_ - ko * s_, k1 = ke * s_ + ko * c_;
    ushort2 h2, l2;
    tsplit(q0, h2.x, l2.x); tsplit(q1, h2.y, l2.y);
    *(ushort2*)&XQh[o] = h2; *(ushort2*)&XQl[o] = l2;
    tsplit(k0, h2.x, l2.x); tsplit(k1, h2.y, l2.y);
    *(ushort2*)&XKh[o] = h2; *(ushort2*)&XKl[o] = l2;
}

// ---------------- per-(b,h,token) ttt_lr ----------------
__global__ __launch_bounds__(256)
void lr_kernel(const float* __restrict__ hidden, const float* __restrict__ lrk,
               const float* __restrict__ lrb, float* __restrict__ lr_buf)
{
    int wave = threadIdx.x >> 6;
    int lane = threadIdx.x & 63;
    int row = blockIdx.x * 4 + wave;
    int b = row >> 12;
    int n = row & (NSEQ - 1);
    const float* hr = hidden + (size_t)row * WIDTH;
    float hv[12];
#pragma unroll
    for (int t = 0; t < 12; t++) hv[t] = hr[lane + 64 * t];
    for (int h = 0; h < HEADS; h++) {
        const float* lk = lrk + h * WIDTH;
        float acc = 0.f;
#pragma unroll
        for (int t = 0; t < 12; t++) acc = fmaf(hv[t], lk[lane + 64 * t], acc);
#pragma unroll
        for (int m = 1; m < 64; m <<= 1) acc += __shfl_xor(acc, m);
        if (lane == 0) {
            float s = 1.0f / (1.0f + __expf(-(acc + lrb[h])));
            lr_buf[((size_t)(b * HEADS + h)) * NSEQ + n] = s * (1.0f / HD);
        }
    }
}

// ---------------- post-norm over 768 + gate multiply, emits hi/lo planes ----------------
__global__ __launch_bounds__(256)
void postgate_kernel(const float* __restrict__ tout, const float* __restrict__ gate,
                     const float* __restrict__ ps, const float* __restrict__ pb,
                     unsigned short* __restrict__ gzh, unsigned short* __restrict__ gzl)
{
    __shared__ float red[8];
    int row = blockIdx.x;
    int tid = threadIdx.x;
    const float* x = tout + (size_t)row * WIDTH;
    float v[3];
    float s1 = 0, s2 = 0;
#pragma unroll
    for (int t = 0; t < 3; t++) { v[t] = x[tid + 256 * t]; s1 += v[t]; s2 += v[t] * v[t]; }
#pragma unroll
    for (int m = 1; m < 64; m <<= 1) { s1 += __shfl_xor(s1, m); s2 += __shfl_xor(s2, m); }
    int wave = tid >> 6, lane = tid & 63;
    if (lane == 0) { red[wave] = s1; red[4 + wave] = s2; }
    __syncthreads();
    s1 = red[0] + red[1] + red[2] + red[3];
    s2 = red[4] + red[5] + red[6] + red[7];
    float mu = s1 * (1.0f / WIDTH);
    float var = s2 * (1.0f / WIDTH) - mu * mu;
    float rstd = rsqrtf(var + EPS);
#pragma unroll
    for (int t = 0; t < 3; t++) {
        int c = tid + 256 * t;
        float z = ps[c] * (v[t] - mu) * rstd + pb[c];
        float gv = gate[(size_t)row * WIDTH + c] * z;
        unsigned short hh, ll; tsplit(gv, hh, ll);
        gzh[(size_t)row * WIDTH + c] = hh;
        gzl[(size_t)row * WIDTH + c] = ll;
    }
}

extern "C" void kernel_launch(void* const* d_in, const int* in_sizes, int n_in,
                              void* d_out, int out_size, void* d_ws, size_t ws_size,
                              hipStream_t stream)
{
    (void)in_sizes; (void)n_in; (void)out_size; (void)ws_size;
    const float* hidden = (const float*)d_in[0];
    const float* wq  = (const float*)d_in[1];
    const float* wv  = (const float*)d_in[2];
    const float* wo  = (const float*)d_in[3];
    const float* wg  = (const float*)d_in[4];
    const float* ckq = (const float*)d_in[5];
    const float* cbq = (const float*)d_in[6];
    const float* ckk = (const float*)d_in[7];
    const float* cbk = (const float*)d_in[8];
    const float* W1  = (const float*)d_in[9];
    const float* b1  = (const float*)d_in[10];
    const float* tns = (const float*)d_in[11];
    const float* tnb = (const float*)d_in[12];
    const float* lrk = (const float*)d_in[13];
    const float* lrb = (const float*)d_in[14];
    const float* lti = (const float*)d_in[15];
    const float* pns = (const float*)d_in[16];
    const float* pnb = (const float*)d_in[17];
    float* out = (float*)d_out;

    const size_t BIG = (size_t)BATCH * NSEQ * WIDTH;   // 12.58M floats
    float* ws  = (float*)d_ws;
    float* xqk = ws;                                   // -> ttt_out (reused after conv_rope)
    float* XVb = ws + BIG;
    unsigned short* XQhi = (unsigned short*)(ws + 2 * BIG);
    unsigned short* XQlo = XQhi + BIG;
    unsigned short* XKhi = (unsigned short*)(ws + 3 * BIG);
    unsigned short* XKlo = XKhi + BIG;
    float* tail = ws + 4 * BIG;
    unsigned short* wThi  = (unsigned short*)tail;          // [2304][768]
    unsigned short* wTlo  = wThi + (size_t)2304 * WIDTH;
    unsigned short* woThi = wTlo + (size_t)2304 * WIDTH;    // [768][768]
    unsigned short* woTlo = woThi + (size_t)WIDTH * WIDTH;
    float* lrbuf = (float*)(woTlo + (size_t)WIDTH * WIDTH);
    unsigned short* gzhi = (unsigned short*)(ws + 2 * BIG); // reuse XQ planes post-scan
    unsigned short* gzlo = gzhi + BIG;
    float* gate = out;    // d_out as scratch until final GEMM
    float* ttto = xqk;

    int M = BATCH * NSEQ;
    wtconv3_kernel<<<dim3(12, 12, 3), 256, 0, stream>>>(wq, wv, wg, wThi, wTlo);
    gemm_qv_kernel<<<dim3(12, M / 128), 256, 0, stream>>>(hidden, wThi, wTlo, xqk, XVb);
    conv_rope_kernel<<<M, 384, 0, stream>>>(xqk, ckq, cbq, ckk, cbk, XQhi, XQlo, XKhi, XKlo);
    lr_kernel<<<M / 4, 256, 0, stream>>>(hidden, lrk, lrb, lrbuf);
    mega_kernel<<<960, 256, 0, stream>>>(XQhi, XQlo, XKhi, XKlo, XVb, lrbuf,
                                         W1, b1, tns, tnb, lti, ttto,
                                         wo, woThi, woTlo,
                                         hidden, wThi + (size_t)1536 * WIDTH,
                                         wTlo + (size_t)1536 * WIDTH, gate);
    postgate_kernel<<<M, 256, 0, stream>>>(ttto, gate, pns, pnb, gzhi, gzlo);
    gemm_out_kernel<<<dim3(6, M / 128), 256, 0, stream>>>(gzhi, gzlo, woThi, woTlo, out);
}